// Round 10
// baseline (241.335 us; speedup 1.0000x reference)
//
#include <hip/hip_runtime.h>
#include <hip/hip_bf16.h>
#include <math.h>

#define NDIM 256
#define NROT 32640          // C(256,2)
#define NSEG 64
#define MATE (NDIM * NDIM)  // elements per plane
#define NODEE (2 * MATE)    // node = hi plane + lo plane (bf16 each)

// cost-balance model for k_build segment boundaries (run i has 255-i rots):
// cost(run i) = BF + BC*(255-i). Closed-form cumulative -> binary search.
#define BF 1280
#define BC 16
#define CSLMAX 1104         // >= worst-case rots/segment (1084) + pad

typedef __bf16 bf16x4_t __attribute__((ext_vector_type(4)));
typedef __bf16 bf16x8_t __attribute__((ext_vector_type(8)));
typedef float f32x4_t __attribute__((ext_vector_type(4)));

// ---------------------------------------------------------------------------
// K2 v3: build 64 segment products applied to I, fp32 in LDS. Segments are
// whole RUNS, boundaries cost-balanced. Output: bf16 hi/lo planes.
// seg%4==0 -> TRANSPOSED ([c][k], seeds the 4-ary chain); else plain.
// ---------------------------------------------------------------------------

#define ROT1(RJ, CS) { float nri_ = fmaf((CS).x, ri, -((CS).y * (RJ))); \
                       (RJ) = fmaf((CS).y, ri, (CS).x * (RJ)); ri = nri_; }

#define LOAD16(P, JB, KK) \
    P##0 = *(const f32x4_t*)&tile[(JB)][t][0]; \
    P##1 = *(const f32x4_t*)&tile[(JB)][t][4]; \
    P##2 = *(const f32x4_t*)&tile[(JB) + 1][t][0]; \
    P##3 = *(const f32x4_t*)&tile[(JB) + 1][t][4]; \
    _Pragma("unroll") \
    for (int u = 0; u < 16; u++) P##c[u] = csl[(KK) + u];

#define COMP16(P, JB) \
    _Pragma("unroll") \
    for (int u = 0; u < 4; u++) ROT1(P##0[u], P##c[u]) \
    _Pragma("unroll") \
    for (int u = 0; u < 4; u++) ROT1(P##1[u], P##c[4 + u]) \
    _Pragma("unroll") \
    for (int u = 0; u < 4; u++) ROT1(P##2[u], P##c[8 + u]) \
    _Pragma("unroll") \
    for (int u = 0; u < 4; u++) ROT1(P##3[u], P##c[12 + u]) \
    *(f32x4_t*)&tile[(JB)][t][0] = P##0; \
    *(f32x4_t*)&tile[(JB)][t][4] = P##1; \
    *(f32x4_t*)&tile[(JB) + 1][t][0] = P##2; \
    *(f32x4_t*)&tile[(JB) + 1][t][4] = P##3;

__device__ __forceinline__ int run_off(int r) {        // rotations before run r
    return 255 * r - (r * (r - 1)) / 2;
}
__device__ __forceinline__ int cum_cost(int r) {       // model cost before run r
    return BF * r + BC * run_off(r);
}
__device__ __forceinline__ int seg_boundary(int s) {   // first run of segment s
    if (s <= 0) return 0;
    if (s >= NSEG) return 255;
    const long target = ((long)cum_cost(255) * s) / NSEG;
    int lo = 0, hi = 255;
    while (lo < hi) {
        int mid = (lo + hi) >> 1;
        if ((long)cum_cost(mid) >= target) hi = mid; else lo = mid + 1;
    }
    return lo;
}

__global__ __launch_bounds__(64, 1) void k_build(const float* __restrict__ rots,
                                                 __bf16* __restrict__ leaves) {
    __shared__ float tile[32][64][8];      // 64 KiB: row r at tile[r>>3][t][r&7]
    __shared__ float2 csl[CSLMAX];
    const int t = threadIdx.x;             // 0..63
    const int seg = blockIdx.x >> 2;
    const int cg_ = blockIdx.x & 3;
    const int col = cg_ * 64 + t;

    const int r0 = seg_boundary(seg);
    const int r1 = seg_boundary(seg + 1);
    const int kg0 = run_off(r0);
    const int nrot = run_off(r1) - kg0;

    // fused sincos: stage this segment's (c,s) into LDS
    for (int u = t; u < nrot; u += 64) {
        float th = rots[kg0 + u];
        float s, c;
        sincosf(th, &s, &c);
        csl[u] = make_float2(c, s);
    }
    for (int u = nrot + t; u < nrot + 16 && u < CSLMAX; u += 64) csl[u] = make_float2(1.f, 0.f);

    // init: identity columns for this column group (b128 writes)
    #pragma unroll
    for (int jb = 0; jb < 32; jb++) {
        f32x4_t z0 = {0.f, 0.f, 0.f, 0.f}, z1 = {0.f, 0.f, 0.f, 0.f};
        if ((col >> 3) == jb) {
            if ((col & 7) < 4) z0[col & 3] = 1.0f;
            else               z1[col & 3] = 1.0f;
        }
        *(f32x4_t*)&tile[jb][t][0] = z0;
        *(f32x4_t*)&tile[jb][t][4] = z1;
    }
    // single wave: LDS ops execute in order, no barrier needed

    float* T = &tile[0][0][0];
    #define TADDR(r) ((((r) >> 3) * 512) + t * 8 + ((r) & 7))

    int k = 0;
    for (int i = r0; i < r1; ++i) {       // whole runs only
        float ri = T[TADDR(i)];
        int j = i + 1;
        int rem = NDIM - j;

        // scalar peel to 8-row alignment
        int npeel = min((8 - (j & 7)) & 7, rem);
        for (int u = 0; u < npeel; u++) {
            float2 cs = csl[k];
            float rj = T[TADDR(j)];
            float nri = fmaf(cs.x, ri, -(cs.y * rj));
            T[TADDR(j)] = fmaf(cs.y, ri, cs.x * rj);
            ri = nri; j++; k++;
        }
        rem -= npeel;

        // 16-rotation batches, A/B double-buffered register prefetch
        if (rem >= 16) {
            int jb = j >> 3;
            f32x4_t A0, A1, A2, A3, B0, B1, B2, B3;
            float2 Ac[16], Bc[16];
            LOAD16(A, jb, k)
            while (rem >= 48) {
                LOAD16(B, jb + 2, k + 16)
                COMP16(A, jb)
                jb += 2; j += 16; k += 16; rem -= 16;
                LOAD16(A, jb + 2, k + 16)
                COMP16(B, jb)
                jb += 2; j += 16; k += 16; rem -= 16;
            }
            if (rem >= 32) {
                LOAD16(B, jb + 2, k + 16)
                COMP16(A, jb)
                jb += 2; j += 16; k += 16; rem -= 16;
                COMP16(B, jb)
                jb += 2; j += 16; k += 16; rem -= 16;
            } else {
                COMP16(A, jb)
                jb += 2; j += 16; k += 16; rem -= 16;
            }
        }

        // 8-rotation cleanup batch
        if (rem >= 8) {
            int jb = j >> 3;
            f32x4_t a0 = *(const f32x4_t*)&tile[jb][t][0];
            f32x4_t a1 = *(const f32x4_t*)&tile[jb][t][4];
            float2 cc[8];
            #pragma unroll
            for (int u = 0; u < 8; u++) cc[u] = csl[k + u];
            #pragma unroll
            for (int u = 0; u < 4; u++) ROT1(a0[u], cc[u])
            #pragma unroll
            for (int u = 0; u < 4; u++) ROT1(a1[u], cc[4 + u])
            *(f32x4_t*)&tile[jb][t][0] = a0;
            *(f32x4_t*)&tile[jb][t][4] = a1;
            j += 8; k += 8; rem -= 8;
        }

        // scalar tail
        while (rem > 0) {
            float2 cs = csl[k];
            float rj = T[TADDR(j)];
            float nri = fmaf(cs.x, ri, -(cs.y * rj));
            T[TADDR(j)] = fmaf(cs.y, ri, cs.x * rj);
            ri = nri; j++; k++; rem--;
        }

        T[TADDR(i)] = ri;
    }
    #undef TADDR

    __bf16* hi = leaves + (size_t)seg * NODEE;
    __bf16* lo = hi + MATE;
    if (seg & 3) {
        // plain [r][col]: scalar 2B stores, coalesced across lanes
        for (int jb = 0; jb < 32; jb++) {
            f32x4_t v0 = *(const f32x4_t*)&tile[jb][t][0];
            f32x4_t v1 = *(const f32x4_t*)&tile[jb][t][4];
            #pragma unroll
            for (int u = 0; u < 8; u++) {
                float v = (u < 4) ? v0[u & 3] : v1[u & 3];
                __bf16 h = (__bf16)v;
                hi[(size_t)(jb * 8 + u) * NDIM + col] = h;
                lo[(size_t)(jb * 8 + u) * NDIM + col] = (__bf16)(v - (float)h);
            }
        }
    } else {
        // transposed [c][k]: contiguous bf16x8 stores per thread-row
        for (int jb = 0; jb < 32; jb++) {
            f32x4_t v0 = *(const f32x4_t*)&tile[jb][t][0];
            f32x4_t v1 = *(const f32x4_t*)&tile[jb][t][4];
            bf16x8_t vh, vl;
            #pragma unroll
            for (int u = 0; u < 8; u++) {
                float v = (u < 4) ? v0[u & 3] : v1[u & 3];
                __bf16 h = (__bf16)v;
                vh[u] = h;
                vl[u] = (__bf16)(v - (float)h);
            }
            *(bf16x8_t*)&hi[(size_t)col * NDIM + jb * 8] = vh;
            *(bf16x8_t*)&lo[(size_t)col * NDIM + jb * 8] = vl;
        }
    }
}

// ---------------------------------------------------------------------------
// K3 v5 (k_quad): 4-ary level, WIDE col-panel geometry. node = c3@c2@c1@c0
// in one dispatch; tree = 3 dispatches (64->16->4->1). Per node: 4 blocks,
// each owns a 64-col panel carried through the 3 chained products in padded
// LDS ping-pong ([64][264], r1-proven stride; bank-balanced). 512 thr/8
// waves; wave owns 32 rows of each product. A (c_pr rows, plain [r][k])
// streamed from global with kc+1 prefetch; each A-frag feeds 12 MFMAs
// (4 nt x 3 hi/lo passes) vs r8's 3 — this fixes r8's 45 us/level geometry.
// Math/parity/store identical to r8 (refcheck'd): c0 transposed seeds the
// panel; output node%4==0 stored transposed; final stores hi only.
// ---------------------------------------------------------------------------
#define LDP 264   // padded panel row (bf16); 528 B
__global__ __launch_bounds__(512, 1) void k_quad(const __bf16* __restrict__ src,
                                                 __bf16* __restrict__ dst,
                                                 int finalLevel) {
    __shared__ __bf16 P[2][2][64 * LDP];   // [buf][hi/lo][col*LDP + k] 132 KB

    const int node = blockIdx.x >> 2;
    const int sid = blockIdx.x & 3;             // 64-col panel id
    const __bf16* c0 = src + (size_t)(4 * node) * NODEE;       // transposed
    const __bf16* a1 = src + (size_t)(4 * node + 1) * NODEE;   // plain
    const __bf16* a2 = src + (size_t)(4 * node + 2) * NODEE;
    const __bf16* a3 = src + (size_t)(4 * node + 3) * NODEE;
    __bf16* Chi = dst + (size_t)node * NODEE;
    __bf16* Clo = Chi + MATE;
    const bool storeT = (!finalLevel) && ((node & 3) == 0);

    const int t = threadIdx.x;
    const int w = t >> 6, lane = t & 63;
    const int lrow = lane & 15, kg = lane >> 4;
    const int r0 = w * 32;                      // this wave's product rows

    // seed: P[0] = c0_T rows [sid*64, +64), both planes (4096 16B chunks)
    #pragma unroll
    for (int q = 0; q < 8; q++) {
        int g = q * 512 + t;
        int pl = g >> 11;             // 2048 chunks per plane
        int c = g & 2047;
        int row = c >> 5, sg = c & 31;
        bf16x8_t v = *(const bf16x8_t*)&c0[(size_t)pl * MATE + (size_t)(sid * 64 + row) * NDIM + sg * 8];
        *(bf16x8_t*)&P[0][pl][row * LDP + sg * 8] = v;
    }
    __syncthreads();

    const __bf16* As[3] = {a1, a2, a3};
    int cur = 0;
    #pragma unroll
    for (int pr = 0; pr < 3; pr++) {
        const __bf16* Ah = As[pr];
        const __bf16* Al = Ah + MATE;
        f32x4_t acc[2][4] = {};
        // A-frag prefetch (kc=0)
        bf16x8_t ah[2], al[2];
        #pragma unroll
        for (int mt = 0; mt < 2; mt++) {
            ah[mt] = *(const bf16x8_t*)&Ah[(size_t)(r0 + mt * 16 + lrow) * NDIM + kg * 8];
            al[mt] = *(const bf16x8_t*)&Al[(size_t)(r0 + mt * 16 + lrow) * NDIM + kg * 8];
        }
        #pragma unroll
        for (int kc = 0; kc < 8; kc++) {
            bf16x8_t nh[2], nl[2];
            if (kc < 7) {
                #pragma unroll
                for (int mt = 0; mt < 2; mt++) {
                    nh[mt] = *(const bf16x8_t*)&Ah[(size_t)(r0 + mt * 16 + lrow) * NDIM + (kc + 1) * 32 + kg * 8];
                    nl[mt] = *(const bf16x8_t*)&Al[(size_t)(r0 + mt * 16 + lrow) * NDIM + (kc + 1) * 32 + kg * 8];
                }
            }
            bf16x8_t bh[4], bl[4];
            #pragma unroll
            for (int nt = 0; nt < 4; nt++) {
                int r = (nt * 16 + lrow) * LDP + kc * 32 + kg * 8;
                bh[nt] = *(const bf16x8_t*)&P[cur][0][r];
                bl[nt] = *(const bf16x8_t*)&P[cur][1][r];
            }
            #pragma unroll
            for (int mt = 0; mt < 2; mt++)
                #pragma unroll
                for (int nt = 0; nt < 4; nt++) {
                    acc[mt][nt] = __builtin_amdgcn_mfma_f32_16x16x32_bf16(ah[mt], bh[nt], acc[mt][nt], 0, 0, 0);
                    acc[mt][nt] = __builtin_amdgcn_mfma_f32_16x16x32_bf16(ah[mt], bl[nt], acc[mt][nt], 0, 0, 0);
                    acc[mt][nt] = __builtin_amdgcn_mfma_f32_16x16x32_bf16(al[mt], bh[nt], acc[mt][nt], 0, 0, 0);
                }
            if (kc < 7) {
                #pragma unroll
                for (int mt = 0; mt < 2; mt++) { ah[mt] = nh[mt]; al[mt] = nl[mt]; }
            }
        }

        if (pr < 2) {
            // split acc -> next panel buffer ([col][k], k = product row)
            const int nxt = cur ^ 1;
            #pragma unroll
            for (int mt = 0; mt < 2; mt++)
                #pragma unroll
                for (int nt = 0; nt < 4; nt++) {
                    bf16x4_t vh, vl;
                    #pragma unroll
                    for (int r = 0; r < 4; r++) {
                        float v = acc[mt][nt][r];
                        __bf16 h = (__bf16)v;
                        vh[r] = h;
                        vl[r] = (__bf16)(v - (float)h);
                    }
                    int kpos = r0 + mt * 16 + kg * 4;
                    *(bf16x4_t*)&P[nxt][0][(nt * 16 + lrow) * LDP + kpos] = vh;
                    *(bf16x4_t*)&P[nxt][1][(nt * 16 + lrow) * LDP + kpos] = vl;
                }
            __syncthreads();
            cur = nxt;
        } else {
            // final product: store node panel to global (r8-verified paths)
            #pragma unroll
            for (int mt = 0; mt < 2; mt++)
                #pragma unroll
                for (int nt = 0; nt < 4; nt++) {
                    int grow = r0 + mt * 16 + kg * 4;
                    int gcol = sid * 64 + nt * 16 + lrow;
                    if (storeT) {
                        bf16x4_t vh, vl;
                        #pragma unroll
                        for (int r = 0; r < 4; r++) {
                            float v = acc[mt][nt][r];
                            __bf16 h = (__bf16)v;
                            vh[r] = h;
                            vl[r] = (__bf16)(v - (float)h);
                        }
                        *(bf16x4_t*)&Chi[(size_t)gcol * NDIM + grow] = vh;
                        *(bf16x4_t*)&Clo[(size_t)gcol * NDIM + grow] = vl;
                    } else if (finalLevel) {
                        #pragma unroll
                        for (int r = 0; r < 4; r++)
                            Chi[(size_t)(grow + r) * NDIM + gcol] = (__bf16)acc[mt][nt][r];
                    } else {
                        #pragma unroll
                        for (int r = 0; r < 4; r++) {
                            float v = acc[mt][nt][r];
                            __bf16 h = (__bf16)v;
                            Chi[(size_t)(grow + r) * NDIM + gcol] = h;
                            Clo[(size_t)(grow + r) * NDIM + gcol] = (__bf16)(v - (float)h);
                        }
                    }
                }
        }
    }
}

// ---------------------------------------------------------------------------
// K4: round-1 GEMM verbatim (proven 43 us, VGPR 84), single 1024-block
// dispatch. Y[b][c] = sum_k X[b][k] * Mhi[c][k]; Mhi = root hi plane.
// BM=BN=128, BK=64 (4 iters), register prefetch of iter+1 global loads,
// 4 waves 2x2 of 64x64, LDS 36 KB.
// ---------------------------------------------------------------------------
#define LDA 72    // padded LDS row (bf16), 144 B
__global__ __launch_bounds__(256, 2) void k_gemm(const float* __restrict__ X,
                                                 const __bf16* __restrict__ Mhi,
                                                 float* __restrict__ Y) {
    __shared__ __bf16 As[128 * LDA];
    __shared__ __bf16 Bs[128 * LDA];
    const int bx = blockIdx.x;
    const int xcd = bx & 7;
    const int q = bx >> 3;
    const int bn = (q & 1) * 128;
    const int bm = (xcd + (q >> 1) * 8) * 128;
    const int t = threadIdx.x;
    const int wid = t >> 6;
    const int lane = t & 63;
    const int wr = (wid >> 1) * 64;
    const int wc = (wid & 1) * 64;
    const int lrow = lane & 15;
    const int kg = lane >> 4;

    f32x4_t acc[4][4] = {};

    f32x4_t ra[8];
    bf16x8_t rb[4];

    // prologue: load iter 0
    #pragma unroll
    for (int qq = 0; qq < 8; qq++) {
        int g = qq * 256 + t;
        ra[qq] = *(const f32x4_t*)&X[(size_t)(bm + (g >> 4)) * 256 + (g & 15) * 4];
    }
    #pragma unroll
    for (int qq = 0; qq < 4; qq++) {
        int g = qq * 256 + t;
        rb[qq] = *(const bf16x8_t*)&Mhi[(size_t)(bn + (g >> 3)) * 256 + (g & 7) * 8];
    }

    #pragma unroll
    for (int it = 0; it < 4; it++) {
        #pragma unroll
        for (int qq = 0; qq < 8; qq++) {
            int g = qq * 256 + t;
            f32x4_t v = ra[qq];
            bf16x4_t h = {(__bf16)v.x, (__bf16)v.y, (__bf16)v.z, (__bf16)v.w};
            *(bf16x4_t*)&As[(g >> 4) * LDA + (g & 15) * 4] = h;
        }
        #pragma unroll
        for (int qq = 0; qq < 4; qq++) {
            int g = qq * 256 + t;
            *(bf16x8_t*)&Bs[(g >> 3) * LDA + (g & 7) * 8] = rb[qq];
        }
        __syncthreads();

        if (it < 3) {
            int kc = (it + 1) * 64;
            #pragma unroll
            for (int qq = 0; qq < 8; qq++) {
                int g = qq * 256 + t;
                ra[qq] = *(const f32x4_t*)&X[(size_t)(bm + (g >> 4)) * 256 + kc + (g & 15) * 4];
            }
            #pragma unroll
            for (int qq = 0; qq < 4; qq++) {
                int g = qq * 256 + t;
                rb[qq] = *(const bf16x8_t*)&Mhi[(size_t)(bn + (g >> 3)) * 256 + kc + (g & 7) * 8];
            }
        }

        #pragma unroll
        for (int k2 = 0; k2 < 2; k2++) {
            bf16x8_t af[4], bfr[4];
            #pragma unroll
            for (int mt = 0; mt < 4; mt++)
                af[mt] = *(const bf16x8_t*)&As[(wr + mt * 16 + lrow) * LDA + k2 * 32 + kg * 8];
            #pragma unroll
            for (int nt = 0; nt < 4; nt++)
                bfr[nt] = *(const bf16x8_t*)&Bs[(wc + nt * 16 + lrow) * LDA + k2 * 32 + kg * 8];
            #pragma unroll
            for (int mt = 0; mt < 4; mt++)
                #pragma unroll
                for (int nt = 0; nt < 4; nt++)
                    acc[mt][nt] = __builtin_amdgcn_mfma_f32_16x16x32_bf16(af[mt], bfr[nt], acc[mt][nt], 0, 0, 0);
        }
        __syncthreads();
    }

    const int ocol = bn + wc + lrow;
    const int orow = bm + wr + kg * 4;
    #pragma unroll
    for (int mt = 0; mt < 4; mt++)
        #pragma unroll
        for (int nt = 0; nt < 4; nt++)
            #pragma unroll
            for (int r = 0; r < 4; r++)
                Y[(size_t)(orow + mt * 16 + r) * 256 + ocol + nt * 16] = acc[mt][nt][r];
}

// ---------------------------------------------------------------------------
// workspace: B0 = 64 nodes x 256 KB = 16 MB; B1 = 16 nodes x 256 KB = 4 MB.
// 4-ary tree: B0(64 leaves) ->B1(16) ->B0(4) ->B1(1 root, hi only) -> gemm.
// ---------------------------------------------------------------------------
extern "C" void kernel_launch(void* const* d_in, const int* in_sizes, int n_in,
                              void* d_out, int out_size, void* d_ws, size_t ws_size,
                              hipStream_t stream) {
    const float* x = (const float*)d_in[0];
    const float* rots = (const float*)d_in[1];
    float* out = (float*)d_out;

    __bf16* B0 = (__bf16*)d_ws;
    __bf16* B1 = B0 + (size_t)NSEG * NODEE;

    k_build<<<NSEG * 4, 64, 0, stream>>>(rots, B0);
    k_quad<<<16 * 4, 512, 0, stream>>>(B0, B1, 0);    // 64 leaves -> 16 nodes
    k_quad<<<4 * 4, 512, 0, stream>>>(B1, B0, 0);     // 16 -> 4
    k_quad<<<1 * 4, 512, 0, stream>>>(B0, B1, 1);     // 4 -> 1 root (hi only)
    k_gemm<<<1024, 256, 0, stream>>>(x, B1, out);
}

// Round 11
// 211.995 us; speedup vs baseline: 1.1384x; 1.1384x over previous
//
#include <hip/hip_runtime.h>
#include <hip/hip_bf16.h>
#include <math.h>

#define NDIM 256
#define NROT 32640          // C(256,2)
#define NSEG 64
#define MATE (NDIM * NDIM)  // elements per plane
#define NODEE (2 * MATE)    // node = hi plane + lo plane (bf16 each)

// cost-balance model for k_build segment boundaries (run i has 255-i rots):
// cost(run i) = BF + BC*(255-i). Closed-form cumulative -> binary search.
#define BF 1280
#define BC 16
#define CSLMAX 1104         // >= worst-case rots/segment (1084) + pad

typedef __bf16 bf16x4_t __attribute__((ext_vector_type(4)));
typedef __bf16 bf16x8_t __attribute__((ext_vector_type(8)));
typedef float f32x4_t __attribute__((ext_vector_type(4)));

typedef __attribute__((address_space(1))) const unsigned int g_u32;
typedef __attribute__((address_space(3))) unsigned int l_u32;

// ---------------------------------------------------------------------------
// K2 v3: build 64 segment products applied to I, fp32 in LDS. Segments are
// whole RUNS, boundaries cost-balanced. Output: bf16 hi/lo planes; even seg
// TRANSPOSED ([c][k]), odd plain ([r][k]).
// ---------------------------------------------------------------------------

#define ROT1(RJ, CS) { float nri_ = fmaf((CS).x, ri, -((CS).y * (RJ))); \
                       (RJ) = fmaf((CS).y, ri, (CS).x * (RJ)); ri = nri_; }

#define LOAD16(P, JB, KK) \
    P##0 = *(const f32x4_t*)&tile[(JB)][t][0]; \
    P##1 = *(const f32x4_t*)&tile[(JB)][t][4]; \
    P##2 = *(const f32x4_t*)&tile[(JB) + 1][t][0]; \
    P##3 = *(const f32x4_t*)&tile[(JB) + 1][t][4]; \
    _Pragma("unroll") \
    for (int u = 0; u < 16; u++) P##c[u] = csl[(KK) + u];

#define COMP16(P, JB) \
    _Pragma("unroll") \
    for (int u = 0; u < 4; u++) ROT1(P##0[u], P##c[u]) \
    _Pragma("unroll") \
    for (int u = 0; u < 4; u++) ROT1(P##1[u], P##c[4 + u]) \
    _Pragma("unroll") \
    for (int u = 0; u < 4; u++) ROT1(P##2[u], P##c[8 + u]) \
    _Pragma("unroll") \
    for (int u = 0; u < 4; u++) ROT1(P##3[u], P##c[12 + u]) \
    *(f32x4_t*)&tile[(JB)][t][0] = P##0; \
    *(f32x4_t*)&tile[(JB)][t][4] = P##1; \
    *(f32x4_t*)&tile[(JB) + 1][t][0] = P##2; \
    *(f32x4_t*)&tile[(JB) + 1][t][4] = P##3;

__device__ __forceinline__ int run_off(int r) {        // rotations before run r
    return 255 * r - (r * (r - 1)) / 2;
}
__device__ __forceinline__ int cum_cost(int r) {       // model cost before run r
    return BF * r + BC * run_off(r);
}
__device__ __forceinline__ int seg_boundary(int s) {   // first run of segment s
    if (s <= 0) return 0;
    if (s >= NSEG) return 255;
    const long target = ((long)cum_cost(255) * s) / NSEG;
    int lo = 0, hi = 255;
    while (lo < hi) {
        int mid = (lo + hi) >> 1;
        if ((long)cum_cost(mid) >= target) hi = mid; else lo = mid + 1;
    }
    return lo;
}

__global__ __launch_bounds__(64, 1) void k_build(const float* __restrict__ rots,
                                                 __bf16* __restrict__ leaves) {
    __shared__ float tile[32][64][8];      // 64 KiB: row r at tile[r>>3][t][r&7]
    __shared__ float2 csl[CSLMAX];
    const int t = threadIdx.x;             // 0..63
    const int seg = blockIdx.x >> 2;
    const int cg_ = blockIdx.x & 3;
    const int col = cg_ * 64 + t;

    const int r0 = seg_boundary(seg);
    const int r1 = seg_boundary(seg + 1);
    const int kg0 = run_off(r0);
    const int nrot = run_off(r1) - kg0;

    // fused sincos: stage this segment's (c,s) into LDS
    for (int u = t; u < nrot; u += 64) {
        float th = rots[kg0 + u];
        float s, c;
        sincosf(th, &s, &c);
        csl[u] = make_float2(c, s);
    }
    for (int u = nrot + t; u < nrot + 16 && u < CSLMAX; u += 64) csl[u] = make_float2(1.f, 0.f);

    // init: identity columns for this column group (b128 writes)
    #pragma unroll
    for (int jb = 0; jb < 32; jb++) {
        f32x4_t z0 = {0.f, 0.f, 0.f, 0.f}, z1 = {0.f, 0.f, 0.f, 0.f};
        if ((col >> 3) == jb) {
            if ((col & 7) < 4) z0[col & 3] = 1.0f;
            else               z1[col & 3] = 1.0f;
        }
        *(f32x4_t*)&tile[jb][t][0] = z0;
        *(f32x4_t*)&tile[jb][t][4] = z1;
    }
    // single wave: LDS ops execute in order, no barrier needed

    float* T = &tile[0][0][0];
    #define TADDR(r) ((((r) >> 3) * 512) + t * 8 + ((r) & 7))

    int k = 0;
    for (int i = r0; i < r1; ++i) {       // whole runs only
        float ri = T[TADDR(i)];
        int j = i + 1;
        int rem = NDIM - j;

        // scalar peel to 8-row alignment
        int npeel = min((8 - (j & 7)) & 7, rem);
        for (int u = 0; u < npeel; u++) {
            float2 cs = csl[k];
            float rj = T[TADDR(j)];
            float nri = fmaf(cs.x, ri, -(cs.y * rj));
            T[TADDR(j)] = fmaf(cs.y, ri, cs.x * rj);
            ri = nri; j++; k++;
        }
        rem -= npeel;

        // 16-rotation batches, A/B double-buffered register prefetch
        if (rem >= 16) {
            int jb = j >> 3;
            f32x4_t A0, A1, A2, A3, B0, B1, B2, B3;
            float2 Ac[16], Bc[16];
            LOAD16(A, jb, k)
            while (rem >= 48) {
                LOAD16(B, jb + 2, k + 16)
                COMP16(A, jb)
                jb += 2; j += 16; k += 16; rem -= 16;
                LOAD16(A, jb + 2, k + 16)
                COMP16(B, jb)
                jb += 2; j += 16; k += 16; rem -= 16;
            }
            if (rem >= 32) {
                LOAD16(B, jb + 2, k + 16)
                COMP16(A, jb)
                jb += 2; j += 16; k += 16; rem -= 16;
                COMP16(B, jb)
                jb += 2; j += 16; k += 16; rem -= 16;
            } else {
                COMP16(A, jb)
                jb += 2; j += 16; k += 16; rem -= 16;
            }
        }

        // 8-rotation cleanup batch
        if (rem >= 8) {
            int jb = j >> 3;
            f32x4_t a0 = *(const f32x4_t*)&tile[jb][t][0];
            f32x4_t a1 = *(const f32x4_t*)&tile[jb][t][4];
            float2 cc[8];
            #pragma unroll
            for (int u = 0; u < 8; u++) cc[u] = csl[k + u];
            #pragma unroll
            for (int u = 0; u < 4; u++) ROT1(a0[u], cc[u])
            #pragma unroll
            for (int u = 0; u < 4; u++) ROT1(a1[u], cc[4 + u])
            *(f32x4_t*)&tile[jb][t][0] = a0;
            *(f32x4_t*)&tile[jb][t][4] = a1;
            j += 8; k += 8; rem -= 8;
        }

        // scalar tail
        while (rem > 0) {
            float2 cs = csl[k];
            float rj = T[TADDR(j)];
            float nri = fmaf(cs.x, ri, -(cs.y * rj));
            T[TADDR(j)] = fmaf(cs.y, ri, cs.x * rj);
            ri = nri; j++; k++; rem--;
        }

        T[TADDR(i)] = ri;
    }
    #undef TADDR

    __bf16* hi = leaves + (size_t)seg * NODEE;
    __bf16* lo = hi + MATE;
    if (seg & 1) {
        // plain [r][col]: scalar 2B stores, coalesced across lanes
        for (int jb = 0; jb < 32; jb++) {
            f32x4_t v0 = *(const f32x4_t*)&tile[jb][t][0];
            f32x4_t v1 = *(const f32x4_t*)&tile[jb][t][4];
            #pragma unroll
            for (int u = 0; u < 8; u++) {
                float v = (u < 4) ? v0[u & 3] : v1[u & 3];
                __bf16 h = (__bf16)v;
                hi[(size_t)(jb * 8 + u) * NDIM + col] = h;
                lo[(size_t)(jb * 8 + u) * NDIM + col] = (__bf16)(v - (float)h);
            }
        }
    } else {
        // transposed [c][k]: contiguous bf16x8 stores per thread-row
        for (int jb = 0; jb < 32; jb++) {
            f32x4_t v0 = *(const f32x4_t*)&tile[jb][t][0];
            f32x4_t v1 = *(const f32x4_t*)&tile[jb][t][4];
            bf16x8_t vh, vl;
            #pragma unroll
            for (int u = 0; u < 8; u++) {
                float v = (u < 4) ? v0[u & 3] : v1[u & 3];
                __bf16 h = (__bf16)v;
                vh[u] = h;
                vl[u] = (__bf16)(v - (float)h);
            }
            *(bf16x8_t*)&hi[(size_t)col * NDIM + jb * 8] = vh;
            *(bf16x8_t*)&lo[(size_t)col * NDIM + jb * 8] = vl;
        }
    }
}

// ---------------------------------------------------------------------------
// K3 v4 (r9-proven, session best): tree combine with async global_load_lds
// staging. LDS = 4 planes x 64 x 256 bf16 = 128 KB LINEAR (gload_lds dest
// must be wave-linear; read aliasing is 2-way = free). 64x64 output, full
// K=256, ONE barrier, 96 MFMAs, hi/lo 3-pass, parity-transposed store.
// node[p] = child[2p+1] @ child[2p]; child[2p] transposed, child[2p+1] plain.
// ---------------------------------------------------------------------------
__global__ __launch_bounds__(256) void k_combine(const __bf16* __restrict__ src,
                                                 __bf16* __restrict__ dst,
                                                 int finalLevel) {
    __shared__ __align__(16) __bf16 planes[4][64 * 256];   // 128 KB, linear

    const int p = blockIdx.x >> 4;
    const int qd = blockIdx.x & 15;
    const int rbq = (qd >> 2) * 64;   // output row base (B rows)
    const int cbq = (qd & 3) * 64;    // output col base (A rows, transposed)
    const __bf16* A = src + (size_t)(2 * p) * NODEE;       // transposed child
    const __bf16* B = src + (size_t)(2 * p + 1) * NODEE;   // plain child
    __bf16* Chi = dst + (size_t)p * NODEE;
    __bf16* Clo = Chi + MATE;
    const bool storeT = (!finalLevel) && ((p & 1) == 0);

    const int t = threadIdx.x;
    const int wid = t >> 6, lane = t & 63;
    const int wr2 = (wid >> 1) * 32, wc2 = (wid & 1) * 32;
    const int lrow = lane & 15, kg = lane >> 4;

    const __bf16* plane_src[4] = {B, B + MATE, A, A + MATE};
    const int plane_row0[4] = {rbq, rbq, cbq, cbq};

    // async stage: wave w stages plane w (64 rows x 256 = 32 KB) as 32 x 1 KB
    {
        const __bf16* gsrc = plane_src[wid] + (size_t)plane_row0[wid] * NDIM + lane * 8;
        __bf16* lbase = &planes[wid][0];
        #pragma unroll
        for (int W = 0; W < 32; W++) {
            __builtin_amdgcn_global_load_lds(
                (g_u32*)(gsrc + W * 512),
                (l_u32*)(lbase + W * 512),    // wave-uniform dest base
                16, 0, 0);
        }
    }
    __syncthreads();   // drains vmcnt (compiler emits the waitcnt)

    f32x4_t acc[2][2] = {};
    #pragma unroll
    for (int kc = 0; kc < 8; kc++) {
        bf16x8_t afh[2], afl[2], bfh[2], bfl[2];
        #pragma unroll
        for (int mt = 0; mt < 2; mt++) {
            int r = (wr2 + mt * 16 + lrow) * 256 + kc * 32 + kg * 8;
            afh[mt] = *(const bf16x8_t*)&planes[0][r];
            afl[mt] = *(const bf16x8_t*)&planes[1][r];
        }
        #pragma unroll
        for (int nt = 0; nt < 2; nt++) {
            int r = (wc2 + nt * 16 + lrow) * 256 + kc * 32 + kg * 8;
            bfh[nt] = *(const bf16x8_t*)&planes[2][r];
            bfl[nt] = *(const bf16x8_t*)&planes[3][r];
        }
        #pragma unroll
        for (int mt = 0; mt < 2; mt++)
            #pragma unroll
            for (int nt = 0; nt < 2; nt++) {
                acc[mt][nt] = __builtin_amdgcn_mfma_f32_16x16x32_bf16(afh[mt], bfh[nt], acc[mt][nt], 0, 0, 0);
                acc[mt][nt] = __builtin_amdgcn_mfma_f32_16x16x32_bf16(afh[mt], bfl[nt], acc[mt][nt], 0, 0, 0);
                acc[mt][nt] = __builtin_amdgcn_mfma_f32_16x16x32_bf16(afl[mt], bfh[nt], acc[mt][nt], 0, 0, 0);
            }
    }

    // C/D: col = lane&15, row = (lane>>4)*4 + reg
    #pragma unroll
    for (int mt = 0; mt < 2; mt++)
        #pragma unroll
        for (int nt = 0; nt < 2; nt++) {
            int grow = rbq + wr2 + mt * 16 + kg * 4;
            int gcol = cbq + wc2 + nt * 16 + lrow;
            if (storeT) {
                bf16x4_t vh, vl;
                #pragma unroll
                for (int r = 0; r < 4; r++) {
                    float v = acc[mt][nt][r];
                    __bf16 h = (__bf16)v;
                    vh[r] = h;
                    vl[r] = (__bf16)(v - (float)h);
                }
                *(bf16x4_t*)&Chi[(size_t)gcol * NDIM + grow] = vh;
                *(bf16x4_t*)&Clo[(size_t)gcol * NDIM + grow] = vl;
            } else if (finalLevel) {
                #pragma unroll
                for (int r = 0; r < 4; r++)
                    Chi[(size_t)(grow + r) * NDIM + gcol] = (__bf16)acc[mt][nt][r];
            } else {
                #pragma unroll
                for (int r = 0; r < 4; r++) {
                    float v = acc[mt][nt][r];
                    __bf16 h = (__bf16)v;
                    Chi[(size_t)(grow + r) * NDIM + gcol] = h;
                    Clo[(size_t)(grow + r) * NDIM + gcol] = (__bf16)(v - (float)h);
                }
            }
        }
}

// ---------------------------------------------------------------------------
// K4 v6: GEMM with global_load_lds staging + XOR-swizzled layout.
// Diagnosis: r1's reg-staged loads give ~25% in-flight duty cycle ->
// Little's-law cap ~2.4 TB/s (43 us). gload_lds = zero-VGPR fire-and-forget
// staging: all 48 KB/iter in flight. gload_lds needs LINEAR LDS dest, so
// bank conflicts are fixed by rule #21: pre-swizzle the GLOBAL source
// address and apply the same XOR on read (dword idx ^= (row&7)<<2) —
// uniform 8 lanes/bank-group -> conflict-free b128 reads.
// A staged as fp32 (convert at read; VALU 4% idle); M staged bf16.
// Geometry/barriers/store identical to r1: BM=BN=128, BK=64, 4 iters,
// 4 waves 2x2 of 64x64. LDS 48 KB -> 3 blocks/CU.
// ---------------------------------------------------------------------------
__global__ __launch_bounds__(256, 2) void k_gemm(const float* __restrict__ X,
                                                 const __bf16* __restrict__ Mhi,
                                                 float* __restrict__ Y) {
    __shared__ __align__(16) float As[128 * 64];      // fp32, swizzled, 32 KB
    __shared__ __align__(16) __bf16 Bs[128 * 64];     // bf16, swizzled, 16 KB
    const int bx = blockIdx.x;
    const int xcd = bx & 7;
    const int q = bx >> 3;
    const int bn = (q & 1) * 128;
    const int bm = (xcd + (q >> 1) * 8) * 128;
    const int t = threadIdx.x;
    const int wid = t >> 6;
    const int lane = t & 63;
    const int wr = (wid >> 1) * 64;
    const int wc = (wid & 1) * 64;
    const int lrow = lane & 15;
    const int kg = lane >> 4;

    f32x4_t acc[4][4] = {};

    #pragma unroll 1
    for (int it = 0; it < 4; it++) {
        const int kb = it * 64;

        // stage A: 32 x 1KB calls (4 rows of 64 dwords each); wave w: calls
        // w*8..w*8+7. lane: rowsub = lane>>4, kx = (lane&15)*4; source dword
        // k = kx ^ ((row&7)<<2)  (involution; write-side of the swizzle).
        {
            const int rsub = lane >> 4;
            const int kx = (lane & 15) * 4;
            #pragma unroll
            for (int c = 0; c < 8; c++) {
                int W = wid * 8 + c;
                int row = W * 4 + rsub;
                int k = kx ^ ((row & 7) << 2);
                const float* gp = &X[(size_t)(bm + row) * 256 + kb + k];
                __builtin_amdgcn_global_load_lds((g_u32*)gp, (l_u32*)&As[W * 256], 16, 0, 0);
            }
        }
        // stage B: 16 x 1KB calls (8 rows of 32 dwords each); wave w: calls
        // w*4..w*4+3. lane: rowsub = lane>>3, kdx = (lane&7)*4 (dword idx).
        {
            const int rsub = lane >> 3;
            const int kdx = (lane & 7) * 4;
            #pragma unroll
            for (int c = 0; c < 4; c++) {
                int W = wid * 4 + c;
                int row = W * 8 + rsub;
                int kd = kdx ^ ((row & 7) << 2);
                const __bf16* gp = &Mhi[(size_t)(bn + row) * 256 + kb + kd * 2];
                __builtin_amdgcn_global_load_lds((g_u32*)gp, (l_u32*)&Bs[W * 512], 16, 0, 0);
            }
        }
        __syncthreads();   // drains vmcnt + sync

        #pragma unroll
        for (int k2 = 0; k2 < 2; k2++) {
            bf16x8_t af[4], bfr[4];
            #pragma unroll
            for (int mt = 0; mt < 4; mt++) {
                int row = wr + mt * 16 + lrow;
                int s4 = (row & 7) << 2;
                int k = k2 * 32 + kg * 8;
                f32x4_t a0 = *(const f32x4_t*)&As[row * 64 + ((k) ^ s4)];
                f32x4_t a1 = *(const f32x4_t*)&As[row * 64 + ((k + 4) ^ s4)];
                af[mt][0] = (__bf16)a0.x; af[mt][1] = (__bf16)a0.y;
                af[mt][2] = (__bf16)a0.z; af[mt][3] = (__bf16)a0.w;
                af[mt][4] = (__bf16)a1.x; af[mt][5] = (__bf16)a1.y;
                af[mt][6] = (__bf16)a1.z; af[mt][7] = (__bf16)a1.w;
            }
            #pragma unroll
            for (int nt = 0; nt < 4; nt++) {
                int row = wc + nt * 16 + lrow;
                int s4 = (row & 7) << 2;
                int kd = k2 * 16 + kg * 4;
                bfr[nt] = *(const bf16x8_t*)&Bs[row * 64 + (kd ^ s4) * 2];
            }
            #pragma unroll
            for (int mt = 0; mt < 4; mt++)
                #pragma unroll
                for (int nt = 0; nt < 4; nt++)
                    acc[mt][nt] = __builtin_amdgcn_mfma_f32_16x16x32_bf16(af[mt], bfr[nt], acc[mt][nt], 0, 0, 0);
        }
        __syncthreads();   // protect LDS before next-iter overwrite
    }

    const int ocol = bn + wc + lrow;
    const int orow = bm + wr + kg * 4;
    #pragma unroll
    for (int mt = 0; mt < 4; mt++)
        #pragma unroll
        for (int nt = 0; nt < 4; nt++)
            #pragma unroll
            for (int r = 0; r < 4; r++)
                Y[(size_t)(orow + mt * 16 + r) * 256 + ocol + nt * 16] = acc[mt][nt][r];
}

// ---------------------------------------------------------------------------
// workspace: B0 = 64 nodes x 256 KB = 16 MB; B1 = 32 nodes x 256 KB = 8 MB.
// tree: B0(64) ->B1(32) ->B0(16) ->B1(8) ->B0(4) ->B1(2) ->B0(1=root, hi only)
// ---------------------------------------------------------------------------
extern "C" void kernel_launch(void* const* d_in, const int* in_sizes, int n_in,
                              void* d_out, int out_size, void* d_ws, size_t ws_size,
                              hipStream_t stream) {
    const float* x = (const float*)d_in[0];
    const float* rots = (const float*)d_in[1];
    float* out = (float*)d_out;

    __bf16* B0 = (__bf16*)d_ws;
    __bf16* B1 = B0 + (size_t)NSEG * NODEE;

    k_build<<<NSEG * 4, 64, 0, stream>>>(rots, B0);
    k_combine<<<32 * 16, 256, 0, stream>>>(B0, B1, 0);
    k_combine<<<16 * 16, 256, 0, stream>>>(B1, B0, 0);
    k_combine<<<8 * 16, 256, 0, stream>>>(B0, B1, 0);
    k_combine<<<4 * 16, 256, 0, stream>>>(B1, B0, 0);
    k_combine<<<2 * 16, 256, 0, stream>>>(B0, B1, 0);
    k_combine<<<1 * 16, 256, 0, stream>>>(B1, B0, 1);
    k_gemm<<<1024, 256, 0, stream>>>(x, B0, out);
}